// Round 6
// baseline (43.810 us; speedup 1.0000x reference)
//
#include <hip/hip_runtime.h>
#include <hip/hip_bf16.h>

typedef __attribute__((ext_vector_type(8))) short short8;
typedef __attribute__((ext_vector_type(4))) float f32x4;

#define N_TOT 8192
#define HALF_B 4096
#define D 128
#define BM 128               // rows per block
#define BN 128               // cols per B-tile step
#define NQ 8                 // column slices (grid.y)
#define SLICE (N_TOT / NQ)   // 1024 cols per block
#define NSTEP (SLICE / BN)   // 8 steps
#define NSLOT 64             // s_part slots per row: [0,8)=row-path cq, [8,64)=col-path bi
// z pre-scaled by SCALE, SCALE^2 = 2*log2(e): z@z^T = sim/T * log2(e)
#define SCALE 1.6986437f
#define LN2 0.69314718f

#if __has_builtin(__builtin_amdgcn_exp2f)
  #define EXP2(x) __builtin_amdgcn_exp2f(x)
#else
  #define EXP2(x) exp2f(x)
#endif

static __device__ inline unsigned short f2bf(float f) {
    unsigned int u = __builtin_bit_cast(unsigned int, f);
    u = (u + 0x7fffu + ((u >> 16) & 1u)) >> 16;
    return (unsigned short)u;
}
static __device__ inline float bf2f(unsigned int b) {
    return __builtin_bit_cast(float, b << 16);
}

// async global->LDS, 16B per lane, LDS dest = wave-uniform base + lane*16
static __device__ __forceinline__ void gload16(const void* g, void* l) {
    __builtin_amdgcn_global_load_lds(
        (const __attribute__((address_space(1))) unsigned int*)g,
        (__attribute__((address_space(3))) unsigned int*)l, 16, 0, 0);
}

// Stage a 128x128 bf16 tile into 32 KB LDS, XOR-swizzled via global source
// (gload_lds writes LDS linearly; swizzle applied to the GLOBAL address).
static __device__ __forceinline__ void stage_tile(const unsigned short* __restrict__ z,
                                                  int src_row, char* ldsbase, int tid) {
    int wv = tid >> 6, ln = tid & 63;
    const char* zb = (const char*)z;
    #pragma unroll
    for (int i = 0; i < 8; ++i) {
        int L  = wv * 8192 + i * 1024;        // wave-uniform LDS byte offset
        int Ll = L + ln * 16;                 // this lane's dest byte
        int r  = Ll >> 8;
        int c2 = (Ll & 255) ^ ((r & 7) << 4);
        gload16(zb + (size_t)(src_row + r) * 256 + c2, ldsbase + L);
    }
}

// swizzled LDS fragment read (16B)
static __device__ __forceinline__ short8 ldsfrag(const char* ldsbase, int row, int kbyte) {
    int off = row * 256 + (kbyte ^ ((row & 7) << 4));
    return *reinterpret_cast<const short8*>(ldsbase + off);
}

// ---- Kernel 1: L2-normalize rows, scale, emit bf16 z [8192][128] ---------
__global__ __launch_bounds__(256) void nrm_k(const float* __restrict__ pi,
                                             const float* __restrict__ pj,
                                             unsigned short* __restrict__ z) {
    int row  = (int)(blockIdx.x * 4) + (int)(threadIdx.x >> 6);
    int lane = (int)threadIdx.x & 63;
    const float* src = (row < HALF_B) ? (pi + (size_t)row * D)
                                      : (pj + (size_t)(row - HALF_B) * D);
    float2 v = *reinterpret_cast<const float2*>(src + lane * 2);
    float ss = v.x * v.x + v.y * v.y;
    #pragma unroll
    for (int off = 32; off >= 1; off >>= 1) ss += __shfl_xor(ss, off);
    float inv = SCALE / fmaxf(sqrtf(ss), 1e-8f);
    unsigned int packed = ((unsigned int)f2bf(v.y * inv) << 16) | (unsigned int)f2bf(v.x * inv);
    *reinterpret_cast<unsigned int*>(z + (size_t)row * D + lane * 2) = packed;
}

// ---- Kernel 2: triangular LDS-staged z@z^T -> exp2 -> row+col sums -------
// grid (64, 8), early-exit below block-diagonal -> 288 active blocks.
// Off-diagonal blocks emit BOTH row sums (their rows) and col sums (their
// cols' rows, by symmetry). Diagonal-slice blocks emit row sums only.
__global__ __launch_bounds__(256, 2) void sim_k(const unsigned short* __restrict__ z,
                                                float* __restrict__ s_part) {
    int bi = (int)blockIdx.x;
    int cq = (int)blockIdx.y;
    if (cq < (bi >> 3)) return;            // below diagonal: covered by symmetry
    bool em = (cq > (bi >> 3));            // emit col sums?

    __shared__ char lds[64 * 1024];
    char* Asm = lds;
    char* Bsm = lds + 32768;
    float* colbuf = (float*)lds;           // reuses Asm region (dead after a-frag read)

    int tid  = (int)threadIdx.x;
    int lane = tid & 63;
    int wid  = tid >> 6;
    int lr   = lane & 15;     // A-row / B-col within 16-tile
    int kg   = lane >> 4;     // k-group
    int R0   = bi * BM;
    int C0   = cq * SLICE;

    stage_tile(z, R0, Asm, tid);
    stage_tile(z, C0, Bsm, tid);
    __syncthreads();

    // A fragments: wave's 32 rows x K=128, read once from LDS (32 VGPRs)
    short8 a[2][4];
    #pragma unroll
    for (int m = 0; m < 2; ++m)
        #pragma unroll
        for (int kt = 0; kt < 4; ++kt)
            a[m][kt] = ldsfrag(Asm, wid * 32 + m * 16 + lr, kg * 16 + kt * 64);
    __syncthreads();   // Asm now dead -> colbuf may be written from here on

    float s[2][4];
    #pragma unroll
    for (int m = 0; m < 2; ++m)
        #pragma unroll
        for (int r = 0; r < 4; ++r) s[m][r] = 0.0f;

    for (int bs = 0; bs < NSTEP; ++bs) {
        if (bs) {
            __syncthreads();                       // readers done with Bsm
            stage_tile(z, C0 + bs * BN, Bsm, tid);
            __syncthreads();                       // stage visible
        }
        #pragma unroll
        for (int nt = 0; nt < 8; ++nt) {
            short8 b[4];
            #pragma unroll
            for (int kt = 0; kt < 4; ++kt)
                b[kt] = ldsfrag(Bsm, nt * 16 + lr, kg * 16 + kt * 64);
            float cs = 0.0f;                       // col partial (this wave's 32 rows)
            #pragma unroll
            for (int m = 0; m < 2; ++m) {
                f32x4 acc = {0.0f, 0.0f, 0.0f, 0.0f};
                #pragma unroll
                for (int kt = 0; kt < 4; ++kt)
                    acc = __builtin_amdgcn_mfma_f32_16x16x32_bf16(a[m][kt], b[kt], acc, 0, 0, 0);
                #pragma unroll
                for (int r = 0; r < 4; ++r) {
                    float ev = EXP2(acc[r]);   // includes diag; fixed in red1_k
                    s[m][r] += ev;
                    cs += ev;
                }
            }
            if (em) {
                cs += __shfl_xor(cs, 16);          // sum over kg (rows)
                cs += __shfl_xor(cs, 32);
                if (kg == 0)
                    colbuf[wid * 1024 + bs * 128 + nt * 16 + lr] = cs;
            }
        }
    }

    // row sums: reduce across the 16 columns held by each 16-lane group
    #pragma unroll
    for (int off = 1; off <= 8; off <<= 1)
        #pragma unroll
        for (int m = 0; m < 2; ++m)
            #pragma unroll
            for (int r = 0; r < 4; ++r)
                s[m][r] += __shfl_xor(s[m][r], off);

    if (lr == 0) {
        int rowbase = R0 + wid * 32;
        #pragma unroll
        for (int m = 0; m < 2; ++m)
            #pragma unroll
            for (int r = 0; r < 4; ++r)
                s_part[(size_t)(rowbase + m * 16 + kg * 4 + r) * NSLOT + cq] = s[m][r];
    }

    if (em) {
        __syncthreads();   // all colbuf writes visible
        #pragma unroll
        for (int u = 0; u < 4; ++u) {
            int col = tid * 4 + (u & 3);   // 256 threads x 4 cols
            // unrolled as 4 independent cols per thread
        }
        int c0 = tid * 4;
        #pragma unroll
        for (int u = 0; u < 4; ++u) {
            int col = c0 + u;
            float v = colbuf[col] + colbuf[1024 + col] + colbuf[2048 + col] + colbuf[3072 + col];
            s_part[(size_t)(C0 + col) * NSLOT + 8 + bi] = v;
        }
    }
}

// ---- Kernel 3: per-row finish, one wave per row --------------------------
// slot lane<8: row-path cq (valid if cq>=g); lane>=8: col-path bi (valid if bi<8g)
__global__ __launch_bounds__(256) void red1_k(const unsigned short* __restrict__ z,
                                              const float* __restrict__ s_part,
                                              float* __restrict__ partial) {
    int wid  = (int)threadIdx.x >> 6;
    int lane = (int)threadIdx.x & 63;
    int row  = (int)blockIdx.x * 4 + wid;
    int g    = row >> 10;

    bool valid = (lane < 8) ? (lane >= g) : ((lane - 8) < (g << 3));
    float S = valid ? s_part[(size_t)row * NSLOT + lane] : 0.0f;

    unsigned int ua = *reinterpret_cast<const unsigned int*>(z + (size_t)row * D + lane * 2);
    unsigned int ub = *reinterpret_cast<const unsigned int*>(z + (size_t)(row ^ HALF_B) * D + lane * 2);
    float a0 = bf2f(ua & 0xffffu), a1 = bf2f(ua >> 16);
    float b0 = bf2f(ub & 0xffffu), b1 = bf2f(ub >> 16);
    float dacc = a0 * a0 + a1 * a1;
    float pacc = a0 * b0 + a1 * b1;

    #pragma unroll
    for (int off = 32; off >= 1; off >>= 1) {
        S    += __shfl_xor(S, off);
        dacc += __shfl_xor(dacc, off);
        pacc += __shfl_xor(pacc, off);
    }
    float Li = __logf(S - EXP2(dacc)) - pacc * LN2;

    __shared__ float ls[4];
    if (lane == 0) ls[wid] = Li;
    __syncthreads();
    if (threadIdx.x == 0)
        partial[blockIdx.x] = ls[0] + ls[1] + ls[2] + ls[3];
}

// ---- Kernel 4: final deterministic sum over 2048 partials ----------------
__global__ __launch_bounds__(1024) void red2_k(const float* __restrict__ partial,
                                               float* __restrict__ out) {
    int tid = (int)threadIdx.x;
    float v = partial[tid] + partial[tid + 1024];
    #pragma unroll
    for (int off = 32; off >= 1; off >>= 1) v += __shfl_xor(v, off);
    __shared__ float ls[16];
    if ((tid & 63) == 0) ls[tid >> 6] = v;
    __syncthreads();
    if (tid < 16) {
        float w = ls[tid];
        #pragma unroll
        for (int off = 8; off >= 1; off >>= 1) w += __shfl_xor(w, off);
        if (tid == 0) out[0] = w * (1.0f / (float)N_TOT);
    }
}

extern "C" void kernel_launch(void* const* d_in, const int* in_sizes, int n_in,
                              void* d_out, int out_size, void* d_ws, size_t ws_size,
                              hipStream_t stream) {
    const float* pi = (const float*)d_in[0];
    const float* pj = (const float*)d_in[1];
    float* out = (float*)d_out;

    unsigned short* z = (unsigned short*)d_ws;                       // 2 MiB
    float* s_part = (float*)((char*)d_ws + (size_t)N_TOT * D * 2);   // 2 MiB ([row][64])
    float* partial = s_part + (size_t)N_TOT * NSLOT;                 // 8 KiB

    nrm_k<<<dim3(N_TOT / 4), dim3(256), 0, stream>>>(pi, pj, z);
    sim_k<<<dim3(N_TOT / BM, NQ), dim3(256), 0, stream>>>(z, s_part);
    red1_k<<<dim3(N_TOT / 4), dim3(256), 0, stream>>>(z, s_part, partial);
    red2_k<<<dim3(1), dim3(1024), 0, stream>>>(partial, out);
}

// Round 7
// 35.828 us; speedup vs baseline: 1.2228x; 1.2228x over previous
//
#include <hip/hip_runtime.h>
#include <hip/hip_bf16.h>

typedef __attribute__((ext_vector_type(8))) short short8;
typedef __attribute__((ext_vector_type(16))) float f32x16;

#define N_TOT 8192
#define HALF_B 4096
#define D 128
#define BM 128               // rows per block
#define BN 64                // cols per B-tile step (double-buffered)
#define NQ 8                 // column slices (grid.y)
#define SLICE (N_TOT / NQ)   // 1024 cols per block
#define NSTEP (SLICE / BN)   // 16 steps
// z pre-scaled by SCALE, SCALE^2 = 2*log2(e): z@z^T = sim/T * log2(e)
#define SCALE 1.6986437f
#define LN2 0.69314718f

#if __has_builtin(__builtin_amdgcn_exp2f)
  #define EXP2(x) __builtin_amdgcn_exp2f(x)
#else
  #define EXP2(x) exp2f(x)
#endif

static __device__ inline unsigned short f2bf(float f) {
    unsigned int u = __builtin_bit_cast(unsigned int, f);
    u = (u + 0x7fffu + ((u >> 16) & 1u)) >> 16;
    return (unsigned short)u;
}
static __device__ inline float bf2f(unsigned int b) {
    return __builtin_bit_cast(float, b << 16);
}

// async global->LDS, 16B per lane, LDS dest = wave-uniform base + lane*16
static __device__ __forceinline__ void gload16(const void* g, void* l) {
    __builtin_amdgcn_global_load_lds(
        (const __attribute__((address_space(1))) unsigned int*)g,
        (__attribute__((address_space(3))) unsigned int*)l, 16, 0, 0);
}

// Stage ROWS x 128 bf16 tile into LDS, XOR-swizzled (row&15)<<4 via the
// GLOBAL source address (gload_lds writes LDS linearly - rule #21).
template<int ROWS>
static __device__ __forceinline__ void stage_rows(const unsigned short* __restrict__ z,
                                                  int src_row, char* ldsbase, int tid) {
    int wv = tid >> 6, ln = tid & 63;
    const char* zb = (const char*)z;
    constexpr int per_wave = ROWS * 256 / 4;   // bytes staged by each of 4 waves
    constexpr int chunks = per_wave / 1024;    // 1 KB per gload16 per wave
    #pragma unroll
    for (int i = 0; i < chunks; ++i) {
        int L  = wv * per_wave + i * 1024;     // wave-uniform LDS byte offset
        int Ll = L + ln * 16;                  // this lane's linear dest byte
        int r  = Ll >> 8;
        int c2 = (Ll & 255) ^ ((r & 15) << 4);
        gload16(zb + (size_t)(src_row + r) * 256 + c2, ldsbase + L);
    }
}

// swizzled LDS fragment read (16B)
static __device__ __forceinline__ short8 ldsfrag(const char* ldsbase, int row, int kbyte) {
    int off = row * 256 + (kbyte ^ ((row & 15) << 4));
    return *reinterpret_cast<const short8*>(ldsbase + off);
}

// ---- Kernel 1: L2-normalize rows, scale, emit bf16 z [8192][128] ---------
__global__ __launch_bounds__(256) void nrm_k(const float* __restrict__ pi,
                                             const float* __restrict__ pj,
                                             unsigned short* __restrict__ z) {
    int row  = (int)(blockIdx.x * 4) + (int)(threadIdx.x >> 6);
    int lane = (int)threadIdx.x & 63;
    const float* src = (row < HALF_B) ? (pi + (size_t)row * D)
                                      : (pj + (size_t)(row - HALF_B) * D);
    float2 v = *reinterpret_cast<const float2*>(src + lane * 2);
    float ss = v.x * v.x + v.y * v.y;
    #pragma unroll
    for (int off = 32; off >= 1; off >>= 1) ss += __shfl_xor(ss, off);
    float inv = SCALE / fmaxf(sqrtf(ss), 1e-8f);
    unsigned int packed = ((unsigned int)f2bf(v.y * inv) << 16) | (unsigned int)f2bf(v.x * inv);
    *reinterpret_cast<unsigned int*>(z + (size_t)row * D + lane * 2) = packed;
}

// ---- Kernel 2: double-buffered LDS z@z^T (32x32 MFMA) -> exp2 -> sums ----
// grid (64, 8), block 256 (4 waves x 32 rows). One barrier per 64-col step;
// next B-half staged before compute so HBM/L2 latency hides under MFMA.
__global__ __launch_bounds__(256, 2) void sim_k(const unsigned short* __restrict__ z,
                                                float* __restrict__ s_part) {
    __shared__ char lds[64 * 1024];
    char* Asm = lds;                 // 32 KB, live whole kernel
    char* B0  = lds + 32768;         // 16 KB
    char* B1  = lds + 49152;         // 16 KB

    int tid  = (int)threadIdx.x;
    int lane = tid & 63;
    int wid  = tid >> 6;
    int lrow = lane & 31;            // A-row / B-col within 32-tile
    int kh   = lane >> 5;            // k-half (8 bf16 each)
    int R0   = (int)blockIdx.x * BM;
    int C0   = (int)blockIdx.y * SLICE;

    stage_rows<128>(z, R0, Asm, tid);
    stage_rows<64>(z, C0, B0, tid);
    __syncthreads();

    // A fragments: wave's 32 rows x K=128, read once from LDS (32 VGPRs)
    short8 a[8];
    #pragma unroll
    for (int ks = 0; ks < 8; ++ks)
        a[ks] = ldsfrag(Asm, wid * 32 + lrow, ks * 32 + kh * 16);

    float s[16];
    #pragma unroll
    for (int r = 0; r < 16; ++r) s[r] = 0.0f;

    char* Bcur = B0;
    char* Bnxt = B1;
    for (int bs = 0; bs < NSTEP; ++bs) {
        if (bs + 1 < NSTEP)
            stage_rows<64>(z, C0 + (bs + 1) * BN, Bnxt, tid);   // prefetch next half
        #pragma unroll
        for (int ct = 0; ct < 2; ++ct) {
            f32x16 acc;
            #pragma unroll
            for (int r = 0; r < 16; ++r) acc[r] = 0.0f;
            #pragma unroll
            for (int ks = 0; ks < 8; ++ks) {
                short8 b = ldsfrag(Bcur, ct * 32 + lrow, ks * 32 + kh * 16);
                acc = __builtin_amdgcn_mfma_f32_32x32x16_bf16(a[ks], b, acc, 0, 0, 0);
            }
            #pragma unroll
            for (int r = 0; r < 16; ++r)
                s[r] += EXP2(acc[r]);   // includes diag; fixed in red1_k
        }
        __syncthreads();               // drains prefetch (vmcnt) + joins readers
        char* t = Bcur; Bcur = Bnxt; Bnxt = t;
    }

    // row sums: reduce across the 32 columns held by each 32-lane group
    #pragma unroll
    for (int off = 1; off <= 16; off <<= 1)
        #pragma unroll
        for (int r = 0; r < 16; ++r)
            s[r] += __shfl_xor(s[r], off);

    // C/D layout (m74/m101): col=lane&31, row=(r&3)+8*(r>>2)+4*(lane>>5)
    if (lrow == 0) {
        int rb = R0 + wid * 32 + kh * 4;
        #pragma unroll
        for (int r = 0; r < 16; ++r)
            s_part[(size_t)(rb + (r & 3) + 8 * (r >> 2)) * NQ + blockIdx.y] = s[r];
    }
}

// ---- Kernel 3: per-row finish, one wave per row --------------------------
__global__ __launch_bounds__(256) void red1_k(const unsigned short* __restrict__ z,
                                              const float* __restrict__ s_part,
                                              float* __restrict__ partial) {
    int wid  = (int)threadIdx.x >> 6;
    int lane = (int)threadIdx.x & 63;
    int row  = (int)blockIdx.x * 4 + wid;

    float S = (lane < NQ) ? s_part[(size_t)row * NQ + lane] : 0.0f;

    unsigned int ua = *reinterpret_cast<const unsigned int*>(z + (size_t)row * D + lane * 2);
    unsigned int ub = *reinterpret_cast<const unsigned int*>(z + (size_t)(row ^ HALF_B) * D + lane * 2);
    float a0 = bf2f(ua & 0xffffu), a1 = bf2f(ua >> 16);
    float b0 = bf2f(ub & 0xffffu), b1 = bf2f(ub >> 16);
    float dacc = a0 * a0 + a1 * a1;
    float pacc = a0 * b0 + a1 * b1;

    #pragma unroll
    for (int off = 32; off >= 1; off >>= 1) {
        S    += __shfl_xor(S, off);
        dacc += __shfl_xor(dacc, off);
        pacc += __shfl_xor(pacc, off);
    }
    float Li = __logf(S - EXP2(dacc)) - pacc * LN2;

    __shared__ float ls[4];
    if (lane == 0) ls[wid] = Li;
    __syncthreads();
    if (threadIdx.x == 0)
        partial[blockIdx.x] = ls[0] + ls[1] + ls[2] + ls[3];
}

// ---- Kernel 4: final deterministic sum over 2048 partials ----------------
__global__ __launch_bounds__(1024) void red2_k(const float* __restrict__ partial,
                                               float* __restrict__ out) {
    int tid = (int)threadIdx.x;
    float v = partial[tid] + partial[tid + 1024];
    #pragma unroll
    for (int off = 32; off >= 1; off >>= 1) v += __shfl_xor(v, off);
    __shared__ float ls[16];
    if ((tid & 63) == 0) ls[tid >> 6] = v;
    __syncthreads();
    if (tid < 16) {
        float w = ls[tid];
        #pragma unroll
        for (int off = 8; off >= 1; off >>= 1) w += __shfl_xor(w, off);
        if (tid == 0) out[0] = w * (1.0f / (float)N_TOT);
    }
}

extern "C" void kernel_launch(void* const* d_in, const int* in_sizes, int n_in,
                              void* d_out, int out_size, void* d_ws, size_t ws_size,
                              hipStream_t stream) {
    const float* pi = (const float*)d_in[0];
    const float* pj = (const float*)d_in[1];
    float* out = (float*)d_out;

    unsigned short* z = (unsigned short*)d_ws;                       // 2 MiB
    float* s_part = (float*)((char*)d_ws + (size_t)N_TOT * D * 2);   // 256 KiB ([row][NQ])
    float* partial = s_part + (size_t)N_TOT * NQ;                    // 8 KiB

    nrm_k<<<dim3(N_TOT / 4), dim3(256), 0, stream>>>(pi, pj, z);
    sim_k<<<dim3(N_TOT / BM, NQ), dim3(256), 0, stream>>>(z, s_part);
    red1_k<<<dim3(N_TOT / 4), dim3(256), 0, stream>>>(z, s_part, partial);
    red2_k<<<dim3(1), dim3(1024), 0, stream>>>(partial, out);
}